// Round 9
// baseline (478.511 us; speedup 1.0000x reference)
//
#include <hip/hip_runtime.h>

typedef __bf16 bf16;
typedef __bf16 bf16x8 __attribute__((ext_vector_type(8)));
typedef __bf16 bf16x4 __attribute__((ext_vector_type(4)));
typedef float  f32x4  __attribute__((ext_vector_type(4)));
typedef float  f32x16 __attribute__((ext_vector_type(16)));
typedef unsigned int u32;
typedef u32 u32x4 __attribute__((ext_vector_type(4)));

#define AS1U(p) ((const __attribute__((address_space(1))) unsigned int*)(p))
#define AS3U(p) ((__attribute__((address_space(3))) unsigned int*)(p))

static __device__ __forceinline__ u32 pack2(float a, float b) {
    unsigned short ua = __builtin_bit_cast(unsigned short, (bf16)a);
    unsigned short ub = __builtin_bit_cast(unsigned short, (bf16)b);
    return (u32)ua | ((u32)ub << 16);
}

// ---------------- 4x transpose + cast fp32 -> bf16 (one launch) -------------
__global__ void transpose_cast4_kernel(const float* __restrict__ W0, const float* __restrict__ W1,
                                       const float* __restrict__ W2, const float* __restrict__ W3,
                                       bf16* __restrict__ D0, bf16* __restrict__ D1,
                                       bf16* __restrict__ D2, bf16* __restrict__ D3) {
    __shared__ float tile[32][33];
    const float* W; bf16* D;
    switch (blockIdx.z) {
        case 0: W = W0; D = D0; break;
        case 1: W = W1; D = D1; break;
        case 2: W = W2; D = D2; break;
        default: W = W3; D = D3; break;
    }
    const int bj = blockIdx.x, bi = blockIdx.y;
    const int tx = threadIdx.x, ty = threadIdx.y;  // 32 x 8
#pragma unroll
    for (int i = 0; i < 4; i++) {
        tile[ty + i * 8][tx] = W[(size_t)(bi * 32 + ty + i * 8) * 1024 + bj * 32 + tx];
    }
    __syncthreads();
#pragma unroll
    for (int i = 0; i < 4; i++) {
        D[(size_t)(bj * 32 + ty + i * 8) * 1024 + bi * 32 + tx] =
            (bf16)tile[tx][ty + i * 8];
    }
}

// ---------------- LayerNorm over 1024, fp32 in -> bf16 out ------------------
__global__ void layernorm_kernel(const float* __restrict__ x,
                                 const float* __restrict__ gamma,
                                 const float* __restrict__ beta,
                                 bf16* __restrict__ h) {
    const int row = blockIdx.x;
    const float* xr = x + (size_t)row * 1024;
    const int t = threadIdx.x;  // 256
    float4 v = ((const float4*)xr)[t];
    float s  = v.x + v.y + v.z + v.w;
    float s2 = v.x * v.x + v.y * v.y + v.z * v.z + v.w * v.w;
#pragma unroll
    for (int m = 1; m < 64; m <<= 1) {
        s  += __shfl_xor(s, m, 64);
        s2 += __shfl_xor(s2, m, 64);
    }
    __shared__ float ssum[4], ssum2[4];
    const int wid = t >> 6, lane = t & 63;
    if (lane == 0) { ssum[wid] = s; ssum2[wid] = s2; }
    __syncthreads();
    s  = ssum[0] + ssum[1] + ssum[2] + ssum[3];
    s2 = ssum2[0] + ssum2[1] + ssum2[2] + ssum2[3];
    const float mu  = s * (1.f / 1024.f);
    const float var = s2 * (1.f / 1024.f) - mu * mu;
    const float rs  = rsqrtf(var + 1e-5f);
    float4 g = ((const float4*)gamma)[t];
    float4 b = ((const float4*)beta)[t];
    bf16x4 o;
    o[0] = (bf16)((v.x - mu) * rs * g.x + b.x);
    o[1] = (bf16)((v.y - mu) * rs * g.y + b.y);
    o[2] = (bf16)((v.z - mu) * rs * g.z + b.z);
    o[3] = (bf16)((v.w - mu) * rs * g.w + b.w);
    ((bf16x4*)(h + (size_t)row * 1024))[t] = o;
}

// ---------------- GEMM: C[M][N] = A[M][K] @ BT[N][K]^T ----------------------
// 128x128 tile, BK=32, 4 waves (each 64x64), mfma 16x16x32 bf16.
// EPI 0: += bias; col<1024: Q, pre-scaled by 0.125*log2(e); 1024..2047: K;
//        col>=2048: relu -> V^T into Vt
// EPI 1: += bo + resid, write fp32
template <int EPI>
__global__ void gemm_kernel(const bf16* __restrict__ A, const bf16* __restrict__ BT,
                            int N, int K,
                            bf16* __restrict__ Cb,
                            const float* __restrict__ b0, const float* __restrict__ b1,
                            const float* __restrict__ b2, bf16* __restrict__ Vt,
                            float* __restrict__ Cf, const float* __restrict__ bo,
                            const float* __restrict__ resid) {
    __shared__ bf16 Asm[128][32];
    __shared__ bf16 Bsm[128][32];
    const int tid = threadIdx.x;
    const int lane = tid & 63, wave = tid >> 6;
    const int wr = wave >> 1, wc = wave & 1;
    const int tileN = blockIdx.x * 128, tileM = blockIdx.y * 128;
    const int row16 = lane & 15, g = lane >> 4;

    f32x4 acc[4][4] = {};

    for (int kt = 0; kt < K; kt += 32) {
#pragma unroll
        for (int i = 0; i < 2; i++) {  // A tile: 512 chunks of 16B
            int c = tid + i * 256;
            int r = c >> 2, cb = (c & 3) * 16;
            const char* g_ = (const char*)(A + (size_t)(tileM + r) * K + kt) + cb;
            char* l_ = (char*)&Asm[0][0] + c * 16;
            __builtin_amdgcn_global_load_lds(AS1U(g_), AS3U(l_), 16, 0, 0);
        }
#pragma unroll
        for (int i = 0; i < 2; i++) {  // B tile
            int c = tid + i * 256;
            int r = c >> 2, cb = (c & 3) * 16;
            const char* g_ = (const char*)(BT + (size_t)(tileN + r) * K + kt) + cb;
            char* l_ = (char*)&Bsm[0][0] + c * 16;
            __builtin_amdgcn_global_load_lds(AS1U(g_), AS3U(l_), 16, 0, 0);
        }
        __syncthreads();
        bf16x8 af[4], bfr[4];
#pragma unroll
        for (int m = 0; m < 4; m++)
            af[m] = *(const bf16x8*)&Asm[wr * 64 + m * 16 + row16][g * 8];
#pragma unroll
        for (int n = 0; n < 4; n++)
            bfr[n] = *(const bf16x8*)&Bsm[wc * 64 + n * 16 + row16][g * 8];
#pragma unroll
        for (int m = 0; m < 4; m++)
#pragma unroll
            for (int n = 0; n < 4; n++)
                acc[m][n] = __builtin_amdgcn_mfma_f32_16x16x32_bf16(af[m], bfr[n],
                                                                   acc[m][n], 0, 0, 0);
        __syncthreads();
    }
#pragma unroll
    for (int m = 0; m < 4; m++) {
        const int row = tileM + wr * 64 + m * 16 + g * 4;
#pragma unroll
        for (int n = 0; n < 4; n++) {
            const int col = tileN + wc * 64 + n * 16 + row16;
            if (EPI == 0 && col >= 2048) {
                // V path: relu, write transposed Vt[b][h][d][t] as bf16x4 over t
                const int d = col - 2048;
                const float bias = b2[d];
                bf16x4 pk;
#pragma unroll
                for (int j = 0; j < 4; j++) {
                    float v = acc[m][n][j] + bias;
                    pk[j] = (bf16)fmaxf(v, 0.f);
                }
                const int bb = row >> 11, tt = row & 2047;
                const int hh = d >> 6, dd = d & 63;
                *(bf16x4*)&Vt[(((size_t)bb * 16 + hh) * 64 + dd) * 2048 + tt] = pk;
            } else {
#pragma unroll
                for (int j = 0; j < 4; j++) {
                    float v = acc[m][n][j];
                    const int r = row + j;
                    if (EPI == 0) {
                        if (col < 1024) {
                            // Q: fold in softmax scale 0.125*log2(e)
                            v = (v + b0[col]) * 0.18033688011112042f;
                        } else {
                            v += b1[col - 1024];
                        }
                        Cb[(size_t)r * N + col] = (bf16)v;
                    } else {
                        v += bo[col] + resid[(size_t)r * N + col];
                        Cf[(size_t)r * N + col] = v;
                    }
                }
            }
        }
    }
}

// ---------------- flash attention, 32x32 MFMA, direct-reg KV, no barriers ---
// grid 1024 blocks (XCD-grouped; exactly 4 blocks/CU, one fully-resident
// round), 256 threads = 4 waves. Block owns 64 q-rows; wave wv covers KV
// tokens [wv*512,(wv+1)*512) for BOTH 32-q subtiles.
// K/V loaded DIRECTLY global->VGPR (no LDS, no barriers in main loop).
// Fixed-max softmax (Q pre-scaled by 0.125*log2(e)): partials combine by
// a 2-phase LDS tree at the end: O = (U0+..+U3)/(l0+..+l3).
__global__ __launch_bounds__(256, 4)
void attn_kernel(const bf16* __restrict__ qkv, const bf16* __restrict__ Vt,
                 bf16* __restrict__ Obuf) {
    const int bid = blockIdx.x;
    const int swz = (bid & 7) * 128 + (bid >> 3);  // 4 heads per XCD
    const int bh = swz >> 5, qt = swz & 31;
    const int b = bh >> 4, h = bh & 15;
    const int qbase = qt * 64;
    const int tid = threadIdx.x;
    const int lane = tid & 63, wv = tid >> 6;  // 4 waves = 4 kv-slices
    const int c = lane & 31, p = lane >> 5;

    __shared__ float ex[2][64][66];  // partial exchange, 2-phase tree (33.8 KB)

    // Q B-frags: qf[su][ch], col q = qbase+su*32+c, d = ch*16 + p*8 + e
    bf16x8 qf[2][4];
#pragma unroll
    for (int su = 0; su < 2; su++) {
        const bf16* qrow = qkv + (size_t)(b * 2048 + qbase + su * 32 + c) * 3072 + h * 64;
#pragma unroll
        for (int ch = 0; ch < 4; ch++)
            qf[su][ch] = *(const bf16x8*)(qrow + ch * 16 + p * 8);
    }

    // K: lane reads token row (tok0 + chunk*32 + c), 16B at d = ch*16 + p*8
    const int tok0 = wv * 512;
    const bf16* kp = qkv + (size_t)b * 2048 * 3072 + 1024 + h * 64
                     + (size_t)(tok0 + c) * 3072 + p * 8;
    // V^T: lane reads d-row (dc*32 + c), 16B at tok = tok0 + chunk*32 + w*16 + p*8
    const bf16* vp = Vt + (size_t)bh * 64 * 2048 + (size_t)c * 2048 + tok0 + p * 8;

    f32x16 accO[2][2] = {};   // [su][dc]
    float l_r[2] = {0.f, 0.f};

    auto loadK = [&](bf16x8 (&kf)[4], int t) {
        const bf16* kt_ = kp + (size_t)t * (32 * 3072);
#pragma unroll
        for (int ch = 0; ch < 4; ch++)
            kf[ch] = *(const bf16x8*)(kt_ + ch * 16);
    };

    auto body = [&](int t, bf16x8 (&kf)[4], bf16x8 (&kn)[4]) {
        // V loads for this chunk issued first: latency covered by QK + softmax
        bf16x8 vf[2][2];
#pragma unroll
        for (int dc = 0; dc < 2; dc++)
#pragma unroll
            for (int w = 0; w < 2; w++)
                vf[dc][w] = *(const bf16x8*)(vp + (size_t)dc * (32 * 2048) + t * 32 + w * 16);

        // QK^T (swapped): accT[su] col q=c, row tok = t*32 + (r&3)+8*(r>>2)+4p
        f32x16 accT[2] = {};
        __builtin_amdgcn_s_setprio(1);
#pragma unroll
        for (int su = 0; su < 2; su++)
#pragma unroll
            for (int ch = 0; ch < 4; ch++)
                accT[su] = __builtin_amdgcn_mfma_f32_32x32x16_bf16(kf[ch], qf[su][ch],
                                                                  accT[su], 0, 0, 0);
        __builtin_amdgcn_s_setprio(0);

        // prefetch next chunk's K while softmax runs
        if (t < 15) loadK(kn, t + 1);

        bf16x8 pf0[2], pf1[2];
#pragma unroll
        for (int su = 0; su < 2; su++) {
            float pv[16];
#pragma unroll
            for (int r = 0; r < 16; r++) pv[r] = exp2f(accT[su][r]);
            float s01 = (pv[0] + pv[1]) + (pv[2] + pv[3]);
            float s23 = (pv[4] + pv[5]) + (pv[6] + pv[7]);
            float s45 = (pv[8] + pv[9]) + (pv[10] + pv[11]);
            float s67 = (pv[12] + pv[13]) + (pv[14] + pv[15]);
            l_r[su] += (s01 + s23) + (s45 + s67);
            u32 k01 = pack2(pv[0], pv[1]),  k23 = pack2(pv[2], pv[3]);
            u32 k45 = pack2(pv[4], pv[5]),  k67 = pack2(pv[6], pv[7]);
            u32 k89 = pack2(pv[8], pv[9]),  kab = pack2(pv[10], pv[11]);
            u32 kcd = pack2(pv[12], pv[13]), kef = pack2(pv[14], pv[15]);
            // v_permlane32_swap_b32 dst, src : dst.lo <-> src.hi
            asm("v_permlane32_swap_b32 %0, %1" : "+v"(k45), "+v"(k01));
            asm("v_permlane32_swap_b32 %0, %1" : "+v"(k67), "+v"(k23));
            asm("v_permlane32_swap_b32 %0, %1" : "+v"(kcd), "+v"(k89));
            asm("v_permlane32_swap_b32 %0, %1" : "+v"(kef), "+v"(kab));
            u32x4 w0w = {k01, k23, k45, k67};
            u32x4 w1w = {k89, kab, kcd, kef};
            pf0[su] = __builtin_bit_cast(bf16x8, w0w);
            pf1[su] = __builtin_bit_cast(bf16x8, w1w);
        }

        // PV: accO[su][dc] += P @ V (K/V frags shared across su)
        __builtin_amdgcn_s_setprio(1);
#pragma unroll
        for (int su = 0; su < 2; su++)
#pragma unroll
            for (int dc = 0; dc < 2; dc++) {
                accO[su][dc] = __builtin_amdgcn_mfma_f32_32x32x16_bf16(pf0[su], vf[dc][0],
                                                                      accO[su][dc], 0, 0, 0);
                accO[su][dc] = __builtin_amdgcn_mfma_f32_32x32x16_bf16(pf1[su], vf[dc][1],
                                                                      accO[su][dc], 0, 0, 0);
            }
        __builtin_amdgcn_s_setprio(0);
    };

    bf16x8 ka[4], kb_[4];
    loadK(ka, 0);
    for (int tt = 0; tt < 8; ++tt) {
        body(2 * tt, ka, kb_);
        body(2 * tt + 1, kb_, ka);
    }

    // ---- combine the 4 kv-slice partials: 2-phase LDS tree ----
    // phase 1: waves 1,3 deposit; waves 0,2 accumulate.
    // phase 2: wave 2 deposits; wave 0 accumulates + epilogue.
    auto deposit = [&](int slot) {
#pragma unroll
        for (int su = 0; su < 2; su++) {
#pragma unroll
            for (int dc = 0; dc < 2; dc++)
#pragma unroll
                for (int r = 0; r < 16; r++)
                    ex[slot][lane][su * 32 + dc * 16 + r] = accO[su][dc][r];
            ex[slot][lane][64 + su] = l_r[su];
        }
    };
    auto accumulate = [&](int slot) {
#pragma unroll
        for (int su = 0; su < 2; su++) {
#pragma unroll
            for (int dc = 0; dc < 2; dc++)
#pragma unroll
                for (int r = 0; r < 16; r++)
                    accO[su][dc][r] += ex[slot][lane][su * 32 + dc * 16 + r];
            l_r[su] += ex[slot][lane][64 + su];
        }
    };

    __syncthreads();
    if (wv == 1) deposit(0);
    if (wv == 3) deposit(1);
    __syncthreads();
    if (wv == 0) accumulate(0);
    if (wv == 2) accumulate(1);
    __syncthreads();
    if (wv == 2) deposit(0);
    __syncthreads();
    if (wv == 0) {
        accumulate(0);
#pragma unroll
        for (int su = 0; su < 2; su++) {
            float lr = l_r[su];
            lr += __shfl_xor(lr, 32);
            const float linv = 1.f / lr;  // for q = qbase + su*32 + c
            float li[16];
#pragma unroll
            for (int r = 0; r < 16; r++)
                li[r] = __shfl(linv, (r & 3) + 8 * (r >> 2) + 4 * p);
            bf16* ob = Obuf + ((size_t)bh * 2048 + qbase + su * 32) * 64;
#pragma unroll
            for (int dc = 0; dc < 2; dc++)
#pragma unroll
                for (int r = 0; r < 16; r++) {
                    const int row = (r & 3) + 8 * (r >> 2) + 4 * p;
                    ob[(size_t)row * 64 + dc * 32 + c] = (bf16)(accO[su][dc][r] * li[r]);
                }
        }
    }
}

extern "C" void kernel_launch(void* const* d_in, const int* in_sizes, int n_in,
                              void* d_out, int out_size, void* d_ws, size_t ws_size,
                              hipStream_t stream) {
    const float* q     = (const float*)d_in[0];
    const float* gamma = (const float*)d_in[3];
    const float* beta  = (const float*)d_in[4];
    const float* Wq    = (const float*)d_in[5];
    const float* bq    = (const float*)d_in[6];
    const float* Wk    = (const float*)d_in[7];
    const float* bk    = (const float*)d_in[8];
    const float* Wv    = (const float*)d_in[9];
    const float* bv    = (const float*)d_in[10];
    const float* Wo    = (const float*)d_in[11];
    const float* bo    = (const float*)d_in[12];
    float* out = (float*)d_out;

    char* ws = (char*)d_ws;
    bf16* h     = (bf16*)(ws);                          // 8 MB
    bf16* WcatT = (bf16*)(ws + (8u << 20));             // 6 MB  [3072][1024]
    bf16* WoT   = (bf16*)(ws + (14u << 20));            // 2 MB  [1024][1024]
    bf16* qkv   = (bf16*)(ws + (16u << 20));            // 24 MB [4096][3072] (Q,K used)
    bf16* Obuf  = (bf16*)(ws + (40u << 20));            // 8 MB  [B][H][T][64]
    bf16* Vtb   = (bf16*)(ws + (48u << 20));            // 8 MB  [B][H][64][T]

    transpose_cast4_kernel<<<dim3(32, 32, 4), dim3(32, 8), 0, stream>>>(
        Wq, Wk, Wv, Wo,
        WcatT, WcatT + (size_t)1024 * 1024, WcatT + (size_t)2048 * 1024, WoT);

    layernorm_kernel<<<4096, 256, 0, stream>>>(q, gamma, beta, h);

    gemm_kernel<0><<<dim3(24, 32), 256, 0, stream>>>(h, WcatT, 3072, 1024,
                                                     qkv, bq, bk, bv, Vtb,
                                                     nullptr, nullptr, nullptr);

    attn_kernel<<<1024, 256, 0, stream>>>(qkv, Vtb, Obuf);

    gemm_kernel<1><<<dim3(8, 32), 256, 0, stream>>>(Obuf, WoT, 1024, 1024,
                                                    nullptr, nullptr, nullptr, nullptr, nullptr,
                                                    out, bo, q);
}

// Round 10
// 151.943 us; speedup vs baseline: 3.1493x; 3.1493x over previous
//
#include <hip/hip_runtime.h>

typedef __bf16 bf16;
typedef __bf16 bf16x8 __attribute__((ext_vector_type(8)));
typedef __bf16 bf16x4 __attribute__((ext_vector_type(4)));
typedef float  f32x4  __attribute__((ext_vector_type(4)));
typedef float  f32x16 __attribute__((ext_vector_type(16)));
typedef unsigned int u32;
typedef u32 u32x4 __attribute__((ext_vector_type(4)));

#define AS1U(p) ((const __attribute__((address_space(1))) unsigned int*)(p))
#define AS3U(p) ((__attribute__((address_space(3))) unsigned int*)(p))

static __device__ __forceinline__ u32 pack2(float a, float b) {
    unsigned short ua = __builtin_bit_cast(unsigned short, (bf16)a);
    unsigned short ub = __builtin_bit_cast(unsigned short, (bf16)b);
    return (u32)ua | ((u32)ub << 16);
}

// ---------------- 4x transpose + cast fp32 -> bf16 (one launch) -------------
__global__ void transpose_cast4_kernel(const float* __restrict__ W0, const float* __restrict__ W1,
                                       const float* __restrict__ W2, const float* __restrict__ W3,
                                       bf16* __restrict__ D0, bf16* __restrict__ D1,
                                       bf16* __restrict__ D2, bf16* __restrict__ D3) {
    __shared__ float tile[32][33];
    const float* W; bf16* D;
    switch (blockIdx.z) {
        case 0: W = W0; D = D0; break;
        case 1: W = W1; D = D1; break;
        case 2: W = W2; D = D2; break;
        default: W = W3; D = D3; break;
    }
    const int bj = blockIdx.x, bi = blockIdx.y;
    const int tx = threadIdx.x, ty = threadIdx.y;  // 32 x 8
#pragma unroll
    for (int i = 0; i < 4; i++) {
        tile[ty + i * 8][tx] = W[(size_t)(bi * 32 + ty + i * 8) * 1024 + bj * 32 + tx];
    }
    __syncthreads();
#pragma unroll
    for (int i = 0; i < 4; i++) {
        D[(size_t)(bj * 32 + ty + i * 8) * 1024 + bi * 32 + tx] =
            (bf16)tile[tx][ty + i * 8];
    }
}

// ---------------- LayerNorm over 1024, fp32 in -> bf16 out ------------------
__global__ void layernorm_kernel(const float* __restrict__ x,
                                 const float* __restrict__ gamma,
                                 const float* __restrict__ beta,
                                 bf16* __restrict__ h) {
    const int row = blockIdx.x;
    const float* xr = x + (size_t)row * 1024;
    const int t = threadIdx.x;  // 256
    float4 v = ((const float4*)xr)[t];
    float s  = v.x + v.y + v.z + v.w;
    float s2 = v.x * v.x + v.y * v.y + v.z * v.z + v.w * v.w;
#pragma unroll
    for (int m = 1; m < 64; m <<= 1) {
        s  += __shfl_xor(s, m, 64);
        s2 += __shfl_xor(s2, m, 64);
    }
    __shared__ float ssum[4], ssum2[4];
    const int wid = t >> 6, lane = t & 63;
    if (lane == 0) { ssum[wid] = s; ssum2[wid] = s2; }
    __syncthreads();
    s  = ssum[0] + ssum[1] + ssum[2] + ssum[3];
    s2 = ssum2[0] + ssum2[1] + ssum2[2] + ssum2[3];
    const float mu  = s * (1.f / 1024.f);
    const float var = s2 * (1.f / 1024.f) - mu * mu;
    const float rs  = rsqrtf(var + 1e-5f);
    float4 g = ((const float4*)gamma)[t];
    float4 b = ((const float4*)beta)[t];
    bf16x4 o;
    o[0] = (bf16)((v.x - mu) * rs * g.x + b.x);
    o[1] = (bf16)((v.y - mu) * rs * g.y + b.y);
    o[2] = (bf16)((v.z - mu) * rs * g.z + b.z);
    o[3] = (bf16)((v.w - mu) * rs * g.w + b.w);
    ((bf16x4*)(h + (size_t)row * 1024))[t] = o;
}

// ---------------- GEMM: C[M][N] = A[M][K] @ BT[N][K]^T ----------------------
// 128x128 tile, BK=32, 4 waves (each 64x64), mfma 16x16x32 bf16.
// EPI 0: += bias; col<1024: Q, pre-scaled by 0.125*log2(e); 1024..2047: K;
//        col>=2048: relu -> V^T into Vt
// EPI 1: += bo + resid, write fp32
template <int EPI>
__global__ void gemm_kernel(const bf16* __restrict__ A, const bf16* __restrict__ BT,
                            int N, int K,
                            bf16* __restrict__ Cb,
                            const float* __restrict__ b0, const float* __restrict__ b1,
                            const float* __restrict__ b2, bf16* __restrict__ Vt,
                            float* __restrict__ Cf, const float* __restrict__ bo,
                            const float* __restrict__ resid) {
    __shared__ bf16 Asm[128][32];
    __shared__ bf16 Bsm[128][32];
    const int tid = threadIdx.x;
    const int lane = tid & 63, wave = tid >> 6;
    const int wr = wave >> 1, wc = wave & 1;
    const int tileN = blockIdx.x * 128, tileM = blockIdx.y * 128;
    const int row16 = lane & 15, g = lane >> 4;

    f32x4 acc[4][4] = {};

    for (int kt = 0; kt < K; kt += 32) {
#pragma unroll
        for (int i = 0; i < 2; i++) {  // A tile: 512 chunks of 16B
            int c = tid + i * 256;
            int r = c >> 2, cb = (c & 3) * 16;
            const char* g_ = (const char*)(A + (size_t)(tileM + r) * K + kt) + cb;
            char* l_ = (char*)&Asm[0][0] + c * 16;
            __builtin_amdgcn_global_load_lds(AS1U(g_), AS3U(l_), 16, 0, 0);
        }
#pragma unroll
        for (int i = 0; i < 2; i++) {  // B tile
            int c = tid + i * 256;
            int r = c >> 2, cb = (c & 3) * 16;
            const char* g_ = (const char*)(BT + (size_t)(tileN + r) * K + kt) + cb;
            char* l_ = (char*)&Bsm[0][0] + c * 16;
            __builtin_amdgcn_global_load_lds(AS1U(g_), AS3U(l_), 16, 0, 0);
        }
        __syncthreads();
        bf16x8 af[4], bfr[4];
#pragma unroll
        for (int m = 0; m < 4; m++)
            af[m] = *(const bf16x8*)&Asm[wr * 64 + m * 16 + row16][g * 8];
#pragma unroll
        for (int n = 0; n < 4; n++)
            bfr[n] = *(const bf16x8*)&Bsm[wc * 64 + n * 16 + row16][g * 8];
#pragma unroll
        for (int m = 0; m < 4; m++)
#pragma unroll
            for (int n = 0; n < 4; n++)
                acc[m][n] = __builtin_amdgcn_mfma_f32_16x16x32_bf16(af[m], bfr[n],
                                                                   acc[m][n], 0, 0, 0);
        __syncthreads();
    }
#pragma unroll
    for (int m = 0; m < 4; m++) {
        const int row = tileM + wr * 64 + m * 16 + g * 4;
#pragma unroll
        for (int n = 0; n < 4; n++) {
            const int col = tileN + wc * 64 + n * 16 + row16;
            if (EPI == 0 && col >= 2048) {
                // V path: relu, write transposed Vt[b][h][d][t] as bf16x4 over t
                const int d = col - 2048;
                const float bias = b2[d];
                bf16x4 pk;
#pragma unroll
                for (int j = 0; j < 4; j++) {
                    float v = acc[m][n][j] + bias;
                    pk[j] = (bf16)fmaxf(v, 0.f);
                }
                const int bb = row >> 11, tt = row & 2047;
                const int hh = d >> 6, dd = d & 63;
                *(bf16x4*)&Vt[(((size_t)bb * 16 + hh) * 64 + dd) * 2048 + tt] = pk;
            } else {
#pragma unroll
                for (int j = 0; j < 4; j++) {
                    float v = acc[m][n][j];
                    const int r = row + j;
                    if (EPI == 0) {
                        if (col < 1024) {
                            // Q: fold in softmax scale 0.125*log2(e)
                            v = (v + b0[col]) * 0.18033688011112042f;
                        } else {
                            v += b1[col - 1024];
                        }
                        Cb[(size_t)r * N + col] = (bf16)v;
                    } else {
                        v += bo[col] + resid[(size_t)r * N + col];
                        Cf[(size_t)r * N + col] = v;
                    }
                }
            }
        }
    }
}

// ---------------- flash attention, 32x32 MFMA, direct-reg KV, no barriers ---
// grid 1024 blocks (XCD-grouped), 256 threads = 4 waves. Block owns 64 q-rows;
// wave wv covers KV tokens [wv*512,(wv+1)*512) for BOTH 32-q subtiles.
// K/V loaded DIRECTLY global->VGPR (no LDS, no barriers in main loop).
// launch_bounds min-waves kept at 2: a 4-bound caps VGPR at 64 and spills the
// ~116-reg working set to scratch (R9: FETCH 770 MB, 400 us). With 116 VGPR
// and 33.8 KB LDS the HW can still co-schedule 4 blocks/CU on its own.
// Fixed-max softmax (Q pre-scaled by 0.125*log2(e)): partials combine by
// a 2-phase LDS tree at the end: O = (U0+..+U3)/(l0+..+l3).
__global__ __launch_bounds__(256, 2)
void attn_kernel(const bf16* __restrict__ qkv, const bf16* __restrict__ Vt,
                 bf16* __restrict__ Obuf) {
    const int bid = blockIdx.x;
    const int swz = (bid & 7) * 128 + (bid >> 3);  // 4 heads per XCD
    const int bh = swz >> 5, qt = swz & 31;
    const int b = bh >> 4, h = bh & 15;
    const int qbase = qt * 64;
    const int tid = threadIdx.x;
    const int lane = tid & 63, wv = tid >> 6;  // 4 waves = 4 kv-slices
    const int c = lane & 31, p = lane >> 5;

    __shared__ float ex[2][64][66];  // partial exchange, 2-phase tree (33.8 KB)

    // Q B-frags: qf[su][ch], col q = qbase+su*32+c, d = ch*16 + p*8 + e
    bf16x8 qf[2][4];
#pragma unroll
    for (int su = 0; su < 2; su++) {
        const bf16* qrow = qkv + (size_t)(b * 2048 + qbase + su * 32 + c) * 3072 + h * 64;
#pragma unroll
        for (int ch = 0; ch < 4; ch++)
            qf[su][ch] = *(const bf16x8*)(qrow + ch * 16 + p * 8);
    }

    // K: lane reads token row (tok0 + chunk*32 + c), 16B at d = ch*16 + p*8
    const int tok0 = wv * 512;
    const bf16* kp = qkv + (size_t)b * 2048 * 3072 + 1024 + h * 64
                     + (size_t)(tok0 + c) * 3072 + p * 8;
    // V^T: lane reads d-row (dc*32 + c), 16B at tok = tok0 + chunk*32 + w*16 + p*8
    const bf16* vp = Vt + (size_t)bh * 64 * 2048 + (size_t)c * 2048 + tok0 + p * 8;

    f32x16 accO[2][2] = {};   // [su][dc]
    float l_r[2] = {0.f, 0.f};

    auto loadK = [&](bf16x8 (&kf)[4], int t) {
        const bf16* kt_ = kp + (size_t)t * (32 * 3072);
#pragma unroll
        for (int ch = 0; ch < 4; ch++)
            kf[ch] = *(const bf16x8*)(kt_ + ch * 16);
    };

    auto body = [&](int t, bf16x8 (&kf)[4], bf16x8 (&kn)[4]) {
        // V loads for this chunk issued first: latency covered by QK + softmax
        bf16x8 vf[2][2];
#pragma unroll
        for (int dc = 0; dc < 2; dc++)
#pragma unroll
            for (int w = 0; w < 2; w++)
                vf[dc][w] = *(const bf16x8*)(vp + (size_t)dc * (32 * 2048) + t * 32 + w * 16);

        // QK^T (swapped): accT[su] col q=c, row tok = t*32 + (r&3)+8*(r>>2)+4p
        f32x16 accT[2] = {};
        __builtin_amdgcn_s_setprio(1);
#pragma unroll
        for (int su = 0; su < 2; su++)
#pragma unroll
            for (int ch = 0; ch < 4; ch++)
                accT[su] = __builtin_amdgcn_mfma_f32_32x32x16_bf16(kf[ch], qf[su][ch],
                                                                  accT[su], 0, 0, 0);
        __builtin_amdgcn_s_setprio(0);

        // prefetch next chunk's K while softmax runs
        if (t < 15) loadK(kn, t + 1);

        bf16x8 pf0[2], pf1[2];
#pragma unroll
        for (int su = 0; su < 2; su++) {
            float pv[16];
#pragma unroll
            for (int r = 0; r < 16; r++) pv[r] = exp2f(accT[su][r]);
            float s01 = (pv[0] + pv[1]) + (pv[2] + pv[3]);
            float s23 = (pv[4] + pv[5]) + (pv[6] + pv[7]);
            float s45 = (pv[8] + pv[9]) + (pv[10] + pv[11]);
            float s67 = (pv[12] + pv[13]) + (pv[14] + pv[15]);
            l_r[su] += (s01 + s23) + (s45 + s67);
            u32 k01 = pack2(pv[0], pv[1]),  k23 = pack2(pv[2], pv[3]);
            u32 k45 = pack2(pv[4], pv[5]),  k67 = pack2(pv[6], pv[7]);
            u32 k89 = pack2(pv[8], pv[9]),  kab = pack2(pv[10], pv[11]);
            u32 kcd = pack2(pv[12], pv[13]), kef = pack2(pv[14], pv[15]);
            // v_permlane32_swap_b32 dst, src : dst.lo <-> src.hi
            asm("v_permlane32_swap_b32 %0, %1" : "+v"(k45), "+v"(k01));
            asm("v_permlane32_swap_b32 %0, %1" : "+v"(k67), "+v"(k23));
            asm("v_permlane32_swap_b32 %0, %1" : "+v"(kcd), "+v"(k89));
            asm("v_permlane32_swap_b32 %0, %1" : "+v"(kef), "+v"(kab));
            u32x4 w0w = {k01, k23, k45, k67};
            u32x4 w1w = {k89, kab, kcd, kef};
            pf0[su] = __builtin_bit_cast(bf16x8, w0w);
            pf1[su] = __builtin_bit_cast(bf16x8, w1w);
        }

        // PV: accO[su][dc] += P @ V (K/V frags shared across su)
        __builtin_amdgcn_s_setprio(1);
#pragma unroll
        for (int su = 0; su < 2; su++)
#pragma unroll
            for (int dc = 0; dc < 2; dc++) {
                accO[su][dc] = __builtin_amdgcn_mfma_f32_32x32x16_bf16(pf0[su], vf[dc][0],
                                                                      accO[su][dc], 0, 0, 0);
                accO[su][dc] = __builtin_amdgcn_mfma_f32_32x32x16_bf16(pf1[su], vf[dc][1],
                                                                      accO[su][dc], 0, 0, 0);
            }
        __builtin_amdgcn_s_setprio(0);
    };

    bf16x8 ka[4], kb_[4];
    loadK(ka, 0);
    for (int tt = 0; tt < 8; ++tt) {
        body(2 * tt, ka, kb_);
        body(2 * tt + 1, kb_, ka);
    }

    // ---- combine the 4 kv-slice partials: 2-phase LDS tree ----
    // phase 1: waves 1,3 deposit; waves 0,2 accumulate.
    // phase 2: wave 2 deposits; wave 0 accumulates + epilogue.
    auto deposit = [&](int slot) {
#pragma unroll
        for (int su = 0; su < 2; su++) {
#pragma unroll
            for (int dc = 0; dc < 2; dc++)
#pragma unroll
                for (int r = 0; r < 16; r++)
                    ex[slot][lane][su * 32 + dc * 16 + r] = accO[su][dc][r];
            ex[slot][lane][64 + su] = l_r[su];
        }
    };
    auto accumulate = [&](int slot) {
#pragma unroll
        for (int su = 0; su < 2; su++) {
#pragma unroll
            for (int dc = 0; dc < 2; dc++)
#pragma unroll
                for (int r = 0; r < 16; r++)
                    accO[su][dc][r] += ex[slot][lane][su * 32 + dc * 16 + r];
            l_r[su] += ex[slot][lane][64 + su];
        }
    };

    __syncthreads();
    if (wv == 1) deposit(0);
    if (wv == 3) deposit(1);
    __syncthreads();
    if (wv == 0) accumulate(0);
    if (wv == 2) accumulate(1);
    __syncthreads();
    if (wv == 2) deposit(0);
    __syncthreads();
    if (wv == 0) {
        accumulate(0);
#pragma unroll
        for (int su = 0; su < 2; su++) {
            float lr = l_r[su];
            lr += __shfl_xor(lr, 32);
            const float linv = 1.f / lr;  // for q = qbase + su*32 + c
            float li[16];
#pragma unroll
            for (int r = 0; r < 16; r++)
                li[r] = __shfl(linv, (r & 3) + 8 * (r >> 2) + 4 * p);
            bf16* ob = Obuf + ((size_t)bh * 2048 + qbase + su * 32) * 64;
#pragma unroll
            for (int dc = 0; dc < 2; dc++)
#pragma unroll
                for (int r = 0; r < 16; r++) {
                    const int row = (r & 3) + 8 * (r >> 2) + 4 * p;
                    ob[(size_t)row * 64 + dc * 32 + c] = (bf16)(accO[su][dc][r] * li[r]);
                }
        }
    }
}

extern "C" void kernel_launch(void* const* d_in, const int* in_sizes, int n_in,
                              void* d_out, int out_size, void* d_ws, size_t ws_size,
                              hipStream_t stream) {
    const float* q     = (const float*)d_in[0];
    const float* gamma = (const float*)d_in[3];
    const float* beta  = (const float*)d_in[4];
    const float* Wq    = (const float*)d_in[5];
    const float* bq    = (const float*)d_in[6];
    const float* Wk    = (const float*)d_in[7];
    const float* bk    = (const float*)d_in[8];
    const float* Wv    = (const float*)d_in[9];
    const float* bv    = (const float*)d_in[10];
    const float* Wo    = (const float*)d_in[11];
    const float* bo    = (const float*)d_in[12];
    float* out = (float*)d_out;

    char* ws = (char*)d_ws;
    bf16* h     = (bf16*)(ws);                          // 8 MB
    bf16* WcatT = (bf16*)(ws + (8u << 20));             // 6 MB  [3072][1024]
    bf16* WoT   = (bf16*)(ws + (14u << 20));            // 2 MB  [1024][1024]
    bf16* qkv   = (bf16*)(ws + (16u << 20));            // 24 MB [4096][3072] (Q,K used)
    bf16* Obuf  = (bf16*)(ws + (40u << 20));            // 8 MB  [B][H][T][64]
    bf16* Vtb   = (bf16*)(ws + (48u << 20));            // 8 MB  [B][H][64][T]

    transpose_cast4_kernel<<<dim3(32, 32, 4), dim3(32, 8), 0, stream>>>(
        Wq, Wk, Wv, Wo,
        WcatT, WcatT + (size_t)1024 * 1024, WcatT + (size_t)2048 * 1024, WoT);

    layernorm_kernel<<<4096, 256, 0, stream>>>(q, gamma, beta, h);

    gemm_kernel<0><<<dim3(24, 32), 256, 0, stream>>>(h, WcatT, 3072, 1024,
                                                     qkv, bq, bk, bv, Vtb,
                                                     nullptr, nullptr, nullptr);

    attn_kernel<<<1024, 256, 0, stream>>>(qkv, Vtb, Obuf);

    gemm_kernel<1><<<dim3(8, 32), 256, 0, stream>>>(Obuf, WoT, 1024, 1024,
                                                    nullptr, nullptr, nullptr, nullptr, nullptr,
                                                    out, bo, q);
}

// Round 11
// 131.182 us; speedup vs baseline: 3.6477x; 1.1583x over previous
//
#include <hip/hip_runtime.h>

typedef __bf16 bf16;
typedef __bf16 bf16x8 __attribute__((ext_vector_type(8)));
typedef __bf16 bf16x4 __attribute__((ext_vector_type(4)));
typedef float  f32x4  __attribute__((ext_vector_type(4)));
typedef float  f32x16 __attribute__((ext_vector_type(16)));
typedef unsigned int u32;
typedef u32 u32x4 __attribute__((ext_vector_type(4)));

#define AS1U(p) ((const __attribute__((address_space(1))) unsigned int*)(p))
#define AS3U(p) ((__attribute__((address_space(3))) unsigned int*)(p))

static __device__ __forceinline__ u32 pack2(float a, float b) {
    unsigned short ua = __builtin_bit_cast(unsigned short, (bf16)a);
    unsigned short ub = __builtin_bit_cast(unsigned short, (bf16)b);
    return (u32)ua | ((u32)ub << 16);
}

// ---------------- 4x transpose + cast fp32 -> bf16 (one launch) -------------
__global__ void transpose_cast4_kernel(const float* __restrict__ W0, const float* __restrict__ W1,
                                       const float* __restrict__ W2, const float* __restrict__ W3,
                                       bf16* __restrict__ D0, bf16* __restrict__ D1,
                                       bf16* __restrict__ D2, bf16* __restrict__ D3) {
    __shared__ float tile[32][33];
    const float* W; bf16* D;
    switch (blockIdx.z) {
        case 0: W = W0; D = D0; break;
        case 1: W = W1; D = D1; break;
        case 2: W = W2; D = D2; break;
        default: W = W3; D = D3; break;
    }
    const int bj = blockIdx.x, bi = blockIdx.y;
    const int tx = threadIdx.x, ty = threadIdx.y;  // 32 x 8
#pragma unroll
    for (int i = 0; i < 4; i++) {
        tile[ty + i * 8][tx] = W[(size_t)(bi * 32 + ty + i * 8) * 1024 + bj * 32 + tx];
    }
    __syncthreads();
#pragma unroll
    for (int i = 0; i < 4; i++) {
        D[(size_t)(bj * 32 + ty + i * 8) * 1024 + bi * 32 + tx] =
            (bf16)tile[tx][ty + i * 8];
    }
}

// ---------------- LayerNorm over 1024, fp32 in -> bf16 out ------------------
__global__ void layernorm_kernel(const float* __restrict__ x,
                                 const float* __restrict__ gamma,
                                 const float* __restrict__ beta,
                                 bf16* __restrict__ h) {
    const int row = blockIdx.x;
    const float* xr = x + (size_t)row * 1024;
    const int t = threadIdx.x;  // 256
    float4 v = ((const float4*)xr)[t];
    float s  = v.x + v.y + v.z + v.w;
    float s2 = v.x * v.x + v.y * v.y + v.z * v.z + v.w * v.w;
#pragma unroll
    for (int m = 1; m < 64; m <<= 1) {
        s  += __shfl_xor(s, m, 64);
        s2 += __shfl_xor(s2, m, 64);
    }
    __shared__ float ssum[4], ssum2[4];
    const int wid = t >> 6, lane = t & 63;
    if (lane == 0) { ssum[wid] = s; ssum2[wid] = s2; }
    __syncthreads();
    s  = ssum[0] + ssum[1] + ssum[2] + ssum[3];
    s2 = ssum2[0] + ssum2[1] + ssum2[2] + ssum2[3];
    const float mu  = s * (1.f / 1024.f);
    const float var = s2 * (1.f / 1024.f) - mu * mu;
    const float rs  = rsqrtf(var + 1e-5f);
    float4 g = ((const float4*)gamma)[t];
    float4 b = ((const float4*)beta)[t];
    bf16x4 o;
    o[0] = (bf16)((v.x - mu) * rs * g.x + b.x);
    o[1] = (bf16)((v.y - mu) * rs * g.y + b.y);
    o[2] = (bf16)((v.z - mu) * rs * g.z + b.z);
    o[3] = (bf16)((v.w - mu) * rs * g.w + b.w);
    ((bf16x4*)(h + (size_t)row * 1024))[t] = o;
}

// ---------------- GEMM: C[M][N] = A[M][K] @ BT[N][K]^T ----------------------
// 128x128 tile, BK=32, 4 waves (each 64x64), mfma 16x16x32 bf16.
// XCD-swizzled grid (nwg % 8 == 0 -> bijective).
// EPI 0: epilogue through per-wave LDS quadrant -> coalesced bf16x8 stores.
//        col<1024: Q (bias, x 0.125*log2(e)); 1024..2047: K (+bias);
//        col>=2048: relu -> V^T into Vt (LDS-transposed, coalesced).
// EPI 1: += bo + resid, write fp32 (original path).
template <int EPI>
__global__ void gemm_kernel(const bf16* __restrict__ A, const bf16* __restrict__ BT,
                            int N, int K,
                            bf16* __restrict__ Cb,
                            const float* __restrict__ b0, const float* __restrict__ b1,
                            const float* __restrict__ b2, bf16* __restrict__ Vt,
                            float* __restrict__ Cf, const float* __restrict__ bo,
                            const float* __restrict__ resid) {
    __shared__ bf16 Asm[128][32];
    __shared__ bf16 Bsm[128][32];
    const int tid = threadIdx.x;
    const int lane = tid & 63, wave = tid >> 6;
    const int wr = wave >> 1, wc = wave & 1;
    // XCD-aware bijective block swizzle
    const int nwg = gridDim.x * gridDim.y;
    const int bid0 = blockIdx.y * gridDim.x + blockIdx.x;
    const int bid = (bid0 & 7) * (nwg >> 3) + (bid0 >> 3);
    const int tileN = (bid % gridDim.x) * 128;
    const int tileM = (bid / gridDim.x) * 128;
    const int row16 = lane & 15, g = lane >> 4;

    f32x4 acc[4][4] = {};

    for (int kt = 0; kt < K; kt += 32) {
#pragma unroll
        for (int i = 0; i < 2; i++) {  // A tile: 512 chunks of 16B
            int c = tid + i * 256;
            int r = c >> 2, cb = (c & 3) * 16;
            const char* g_ = (const char*)(A + (size_t)(tileM + r) * K + kt) + cb;
            char* l_ = (char*)&Asm[0][0] + c * 16;
            __builtin_amdgcn_global_load_lds(AS1U(g_), AS3U(l_), 16, 0, 0);
        }
#pragma unroll
        for (int i = 0; i < 2; i++) {  // B tile
            int c = tid + i * 256;
            int r = c >> 2, cb = (c & 3) * 16;
            const char* g_ = (const char*)(BT + (size_t)(tileN + r) * K + kt) + cb;
            char* l_ = (char*)&Bsm[0][0] + c * 16;
            __builtin_amdgcn_global_load_lds(AS1U(g_), AS3U(l_), 16, 0, 0);
        }
        __syncthreads();
        bf16x8 af[4], bfr[4];
#pragma unroll
        for (int m = 0; m < 4; m++)
            af[m] = *(const bf16x8*)&Asm[wr * 64 + m * 16 + row16][g * 8];
#pragma unroll
        for (int n = 0; n < 4; n++)
            bfr[n] = *(const bf16x8*)&Bsm[wc * 64 + n * 16 + row16][g * 8];
#pragma unroll
        for (int m = 0; m < 4; m++)
#pragma unroll
            for (int n = 0; n < 4; n++)
                acc[m][n] = __builtin_amdgcn_mfma_f32_16x16x32_bf16(af[m], bfr[n],
                                                                   acc[m][n], 0, 0, 0);
        __syncthreads();
    }

    if constexpr (EPI == 0) {
        // ---- epilogue via per-wave 8KB LDS quadrant (no cross-wave sync) ----
        __shared__ bf16 Ep[4][64][64];
        char* ep = (char*)&Ep[wave][0][0];
        const bool isV = (tileN >= 2048);
        if (!isV) {
            // write [row][col] with XOR swizzle; bias+scale applied here
#pragma unroll
            for (int n = 0; n < 4; n++) {
                const int cl = n * 16 + row16;
                const int gc = tileN + wc * 64 + cl;
                const float bias = gc < 1024 ? b0[gc] : b1[gc - 1024];
                const float scl = gc < 1024 ? 0.18033688011112042f : 1.f;
#pragma unroll
                for (int m = 0; m < 4; m++)
#pragma unroll
                    for (int j = 0; j < 4; j++) {
                        const int rl = m * 16 + g * 4 + j;
                        const float v = (acc[m][n][j] + bias) * scl;
                        *(bf16*)(ep + rl * 128 + ((cl * 2) ^ ((rl & 7) << 4))) = (bf16)v;
                    }
            }
        } else {
            // write transposed [d][t] with XOR swizzle; bias+relu applied here
#pragma unroll
            for (int n = 0; n < 4; n++) {
                const int dl = n * 16 + row16;
                const float bias = b2[(tileN - 2048) + wc * 64 + dl];
#pragma unroll
                for (int m = 0; m < 4; m++)
#pragma unroll
                    for (int j = 0; j < 4; j++) {
                        const int tl = m * 16 + g * 4 + j;
                        const float v = fmaxf(acc[m][n][j] + bias, 0.f);
                        *(bf16*)(ep + dl * 128 + ((tl * 2) ^ ((dl & 7) << 4))) = (bf16)v;
                    }
            }
        }
        asm volatile("s_waitcnt lgkmcnt(0)" ::: "memory");
        __builtin_amdgcn_sched_barrier(0);
        if (!isV) {
#pragma unroll
            for (int it = 0; it < 8; it++) {
                const int rl = (lane >> 3) + it * 8;
                const bf16x8 vrow = *(const bf16x8*)(ep + rl * 128 +
                                                     (((lane & 7) * 16) ^ ((rl & 7) << 4)));
                const int gr = tileM + wr * 64 + rl;
                const int gc = tileN + wc * 64 + (lane & 7) * 8;
                *(bf16x8*)&Cb[(size_t)gr * N + gc] = vrow;
            }
        } else {
            const int bb = tileM >> 11;
            const int tbase = (tileM & 2047) + wr * 64 + (lane & 7) * 8;
#pragma unroll
            for (int it = 0; it < 8; it++) {
                const int dl = (lane >> 3) + it * 8;
                const bf16x8 vrow = *(const bf16x8*)(ep + dl * 128 +
                                                     (((lane & 7) * 16) ^ ((dl & 7) << 4)));
                const int gd = (tileN - 2048) + wc * 64 + dl;
                const int hh = gd >> 6, dd = gd & 63;
                *(bf16x8*)&Vt[(((size_t)bb * 16 + hh) * 64 + dd) * 2048 + tbase] = vrow;
            }
        }
    } else {
        // EPI 1: += bo + resid, write fp32 (original scalar path)
#pragma unroll
        for (int m = 0; m < 4; m++) {
            const int row = tileM + wr * 64 + m * 16 + g * 4;
#pragma unroll
            for (int n = 0; n < 4; n++) {
                const int col = tileN + wc * 64 + n * 16 + row16;
#pragma unroll
                for (int j = 0; j < 4; j++) {
                    const int r = row + j;
                    Cf[(size_t)r * N + col] = acc[m][n][j] + bo[col] +
                                              resid[(size_t)r * N + col];
                }
            }
        }
    }
}

// ---------------- flash attention, 32x32 MFMA, in-block KV split (R7) -------
// grid 512 blocks (XCD-grouped), 512 threads = 8 waves.
// Waves 0-3: q-subtiles x KV[0,1024); waves 4-7: same q x KV[1024,2048).
// Fixed-max softmax (Q pre-scaled by 0.125*log2(e)) -> partials combine by
// simple addition in LDS at the end: O = (U0+U1)/(l0+l1).
__global__ __launch_bounds__(512, 4)
void attn_kernel(const bf16* __restrict__ qkv, const bf16* __restrict__ Vt,
                 bf16* __restrict__ Obuf) {
    const int bid = blockIdx.x;
    const int swz = (bid & 7) * 64 + (bid >> 3);  // 4 heads per XCD
    const int bh = swz >> 4, qt = swz & 15;
    const int b = bh >> 4, h = bh & 15;
    const int qbase = qt * 128;
    const int tid = threadIdx.x;
    const int lane = tid & 63, wv = tid >> 6;      // 8 waves
    const int half = wv >> 2, qw = wv & 3;
    const int c = lane & 31, p = lane >> 5;

    __shared__ bf16 Kl[2][2][64][64];  // [half][slot] 32 KB
    __shared__ bf16 Vl[2][2][64][64];  // [half][slot] 32 KB

    // Q B-frags (col q = c, k: d = ch*16 + p*8 + j), loop-invariant
    const bf16* qrow = qkv + (size_t)(b * 2048 + qbase + qw * 32 + c) * 3072 + h * 64;
    bf16x8 qf[4];
#pragma unroll
    for (int ch = 0; ch < 4; ch++)
        qf[ch] = *(const bf16x8*)(qrow + ch * 16 + p * 8);

    // staging: each half's 256 threads stage their half's K,V tile (4x16B each)
    const char* kgbase = (const char*)(qkv + (size_t)b * 2048 * 3072 + 1024 + h * 64)
                         + (size_t)(half * 1024) * 6144;
    const char* vgbase = (const char*)(Vt + (size_t)bh * 64 * 2048) + half * 2048;
    const int ht = tid & 255;
    const char* kgp[2]; const char* vgp[2]; int ldo[2];
#pragma unroll
    for (int i = 0; i < 2; i++) {
        const int cc = ht + i * 256;
        const int srow = cc >> 3;
        const int scol = ((cc & 7) * 16) ^ ((srow & 7) << 4);
        kgp[i] = kgbase + (size_t)srow * 6144 + scol;  // srow = token
        vgp[i] = vgbase + (size_t)srow * 4096 + scol;  // srow = d; scol = tok bytes
        ldo[i] = cc * 16;
    }
    char* kldb = (char*)&Kl[half][0][0][0];
    char* vldb = (char*)&Vl[half][0][0][0];

    auto stage = [&](int t, int slot) {
        const size_t ko = (size_t)t * (64 * 6144);  // 64 tokens fwd in qkv
        const size_t vo = (size_t)t * 128;          // 64 tokens * 2B fwd in Vt
        const int sb = slot * 8192;
#pragma unroll
        for (int i = 0; i < 2; i++) {
            __builtin_amdgcn_global_load_lds(AS1U(kgp[i] + ko), AS3U(kldb + sb + ldo[i]), 16, 0, 0);
            __builtin_amdgcn_global_load_lds(AS1U(vgp[i] + vo), AS3U(vldb + sb + ldo[i]), 16, 0, 0);
        }
    };

    f32x16 accO[2] = {};
    float l_r = 0.f;

    auto compute = [&](int slot) {
        const char* Kb = (const char*)&Kl[half][slot][0][0];
        const char* Vb = (const char*)&Vl[half][slot][0][0];
#pragma unroll
        for (int cc = 0; cc < 2; cc++) {
            // S^T = K @ Q^T : col q = c, row tok = cc*32 + (r&3)+8*(r>>2)+4*p
            f32x16 accT = {};
            const int tok = cc * 32 + c;  // A-frag row
#pragma unroll
            for (int ch = 0; ch < 4; ch++) {
                const bf16x8 kf = *(const bf16x8*)(Kb + tok * 128 +
                                                   ((ch * 32 + p * 16) ^ ((tok & 7) << 4)));
                accT = __builtin_amdgcn_mfma_f32_32x32x16_bf16(kf, qf[ch], accT, 0, 0, 0);
            }
            // fixed-max softmax: P = exp2(S) (Q pre-scaled), per-lane partial l
            float pv[16];
#pragma unroll
            for (int r = 0; r < 16; r++) pv[r] = exp2f(accT[r]);
            float s01 = (pv[0] + pv[1]) + (pv[2] + pv[3]);
            float s23 = (pv[4] + pv[5]) + (pv[6] + pv[7]);
            float s45 = (pv[8] + pv[9]) + (pv[10] + pv[11]);
            float s67 = (pv[12] + pv[13]) + (pv[14] + pv[15]);
            l_r += (s01 + s23) + (s45 + s67);
            // pack to bf16 pairs (tok order (0,1),(2,3),... per lane)
            u32 k01 = pack2(pv[0], pv[1]),  k23 = pack2(pv[2], pv[3]);
            u32 k45 = pack2(pv[4], pv[5]),  k67 = pack2(pv[6], pv[7]);
            u32 k89 = pack2(pv[8], pv[9]),  kab = pack2(pv[10], pv[11]);
            u32 kcd = pack2(pv[12], pv[13]), kef = pack2(pv[14], pv[15]);
            // v_permlane32_swap_b32 dst, src : dst.lo <-> src.hi
            asm("v_permlane32_swap_b32 %0, %1" : "+v"(k45), "+v"(k01));
            asm("v_permlane32_swap_b32 %0, %1" : "+v"(k67), "+v"(k23));
            asm("v_permlane32_swap_b32 %0, %1" : "+v"(kcd), "+v"(k89));
            asm("v_permlane32_swap_b32 %0, %1" : "+v"(kef), "+v"(kab));
            u32x4 w0w = {k01, k23, k45, k67};
            u32x4 w1w = {k89, kab, kcd, kef};
            const bf16x8 pf0 = __builtin_bit_cast(bf16x8, w0w);
            const bf16x8 pf1 = __builtin_bit_cast(bf16x8, w1w);
            // PV: O[q][d] += P @ V ; B-frag: col d = dc*32+c, k tok = cc*32+w*16+p*8+j
#pragma unroll
            for (int dc = 0; dc < 2; dc++) {
                const int rd = dc * 32 + c;
                const int sw = (rd & 7) << 4;
                const bf16x8 vf0 = *(const bf16x8*)(Vb + rd * 128 + ((cc * 64 + p * 16) ^ sw));
                const bf16x8 vf1 = *(const bf16x8*)(Vb + rd * 128 + ((cc * 64 + 32 + p * 16) ^ sw));
                accO[dc] = __builtin_amdgcn_mfma_f32_32x32x16_bf16(pf0, vf0, accO[dc], 0, 0, 0);
                accO[dc] = __builtin_amdgcn_mfma_f32_32x32x16_bf16(pf1, vf1, accO[dc], 0, 0, 0);
            }
        }
    };

#define KV_SYNC() do { \
        asm volatile("s_waitcnt vmcnt(0)" ::: "memory"); \
        __builtin_amdgcn_s_barrier(); \
        asm volatile("" ::: "memory"); \
    } while (0)

    stage(0, 0);
#pragma unroll 1
    for (int t = 0; t < 14; t += 2) {
        KV_SYNC(); stage(t + 1, 1); compute(0);
        KV_SYNC(); stage(t + 2, 0); compute(1);
    }
    KV_SYNC(); stage(15, 1); compute(0);
    KV_SYNC(); compute(1);
#undef KV_SYNC

    // ---- combine the two KV halves via LDS (reuse ring memory) ----
    __syncthreads();
    float* ex = (float*)&Kl[0][0][0][0];  // 33.8 KB of 64 KB
    const int xb = (qw * 64 + lane) * 33;  // stride 33 -> conflict-free
    if (half) {
#pragma unroll
        for (int dc = 0; dc < 2; dc++)
#pragma unroll
            for (int r = 0; r < 16; r++) ex[xb + dc * 16 + r] = accO[dc][r];
        ex[xb + 32] = l_r;
    }
    __syncthreads();
    if (!half) {
#pragma unroll
        for (int dc = 0; dc < 2; dc++)
#pragma unroll
            for (int r = 0; r < 16; r++) accO[dc][r] += ex[xb + dc * 16 + r];
        l_r += ex[xb + 32];
        // finish l across p-halves, O /= l, store [b][h][t][d] bf16
        l_r += __shfl_xor(l_r, 32);
        const float linv = 1.f / l_r;  // valid for q = c (both halves)
        float li[16];
#pragma unroll
        for (int r = 0; r < 16; r++)
            li[r] = __shfl(linv, (r & 3) + 8 * (r >> 2) + 4 * p);
        bf16* ob = Obuf + ((size_t)bh * 2048 + qbase + qw * 32) * 64;
#pragma unroll
        for (int dc = 0; dc < 2; dc++)
#pragma unroll
            for (int r = 0; r < 16; r++) {
                const int row = (r & 3) + 8 * (r >> 2) + 4 * p;
                ob[(size_t)row * 64 + dc * 32 + c] = (bf16)(accO[dc][r] * li[r]);
            }
    }
}

extern "C" void kernel_launch(void* const* d_in, const int* in_sizes, int n_in,
                              void* d_out, int out_size, void* d_ws, size_t ws_size,
                              hipStream_t stream) {
    const float* q     = (const float*)d_in[0];
    const float* gamma = (const float*)d_in[3];
    const float* beta  = (const float*)d_in[4];
    const float* Wq    = (const float*)d_in[5];
    const float* bq    = (const float*)d_in[6];
    const float* Wk    = (const float*)d_in[7];
    const float* bk    = (const float*)d_in[8];
    const float* Wv    = (const float*)d_in[9];
    const float* bv    = (const float*)d_in[10];
    const float* Wo    = (const float*)d_in[11];
    const float* bo    = (const float*)d_in[12];
    float* out = (float*)d_out;

    char* ws = (char*)d_ws;
    bf16* h     = (bf16*)(ws);                          // 8 MB
    bf16* WcatT = (bf16*)(ws + (8u << 20));             // 6 MB  [3072][1024]
    bf16* WoT   = (bf16*)(ws + (14u << 20));            // 2 MB  [1024][1024]
    bf16* qkv   = (bf16*)(ws + (16u << 20));            // 24 MB [4096][3072] (Q,K used)
    bf16* Obuf  = (bf16*)(ws + (40u << 20));            // 8 MB  [B][H][T][64]
    bf16* Vtb   = (bf16*)(ws + (48u << 20));            // 8 MB  [B][H][64][T]

    transpose_cast4_kernel<<<dim3(32, 32, 4), dim3(32, 8), 0, stream>>>(
        Wq, Wk, Wv, Wo,
        WcatT, WcatT + (size_t)1024 * 1024, WcatT + (size_t)2048 * 1024, WoT);

    layernorm_kernel<<<4096, 256, 0, stream>>>(q, gamma, beta, h);

    gemm_kernel<0><<<dim3(24, 32), 256, 0, stream>>>(h, WcatT, 3072, 1024,
                                                     qkv, bq, bk, bv, Vtb,
                                                     nullptr, nullptr, nullptr);

    attn_kernel<<<512, 512, 0, stream>>>(qkv, Vtb, Obuf);

    gemm_kernel<1><<<dim3(8, 32), 256, 0, stream>>>(Obuf, WoT, 1024, 1024,
                                                    nullptr, nullptr, nullptr, nullptr, nullptr,
                                                    out, bo, q);
}

// Round 12
// 128.141 us; speedup vs baseline: 3.7343x; 1.0237x over previous
//
#include <hip/hip_runtime.h>

typedef __bf16 bf16;
typedef __bf16 bf16x8 __attribute__((ext_vector_type(8)));
typedef __bf16 bf16x4 __attribute__((ext_vector_type(4)));
typedef float  f32x4  __attribute__((ext_vector_type(4)));
typedef float  f32x16 __attribute__((ext_vector_type(16)));
typedef unsigned int u32;
typedef u32 u32x4 __attribute__((ext_vector_type(4)));

#define AS1U(p) ((const __attribute__((address_space(1))) unsigned int*)(p))
#define AS3U(p) ((__attribute__((address_space(3))) unsigned int*)(p))

static __device__ __forceinline__ u32 pack2(float a, float b) {
    unsigned short ua = __builtin_bit_cast(unsigned short, (bf16)a);
    unsigned short ub = __builtin_bit_cast(unsigned short, (bf16)b);
    return (u32)ua | ((u32)ub << 16);
}

// ---------------- fused: LayerNorm (blocks 0..4095) + 4x W transpose --------
__global__ void prep_kernel(const float* __restrict__ q,
                            const float* __restrict__ gamma,
                            const float* __restrict__ beta,
                            bf16* __restrict__ h,
                            const float* __restrict__ W0, const float* __restrict__ W1,
                            const float* __restrict__ W2, const float* __restrict__ W3,
                            bf16* __restrict__ D0, bf16* __restrict__ D1,
                            bf16* __restrict__ D2, bf16* __restrict__ D3) {
    __shared__ float tile[32][33];
    __shared__ float ssum[4], ssum2[4];
    const int blk = blockIdx.x;
    const int t = threadIdx.x;  // 256
    if (blk < 4096) {
        // ---- LayerNorm over 1024, fp32 in -> bf16 out ----
        const float* xr = q + (size_t)blk * 1024;
        float4 v = ((const float4*)xr)[t];
        float s  = v.x + v.y + v.z + v.w;
        float s2 = v.x * v.x + v.y * v.y + v.z * v.z + v.w * v.w;
#pragma unroll
        for (int m = 1; m < 64; m <<= 1) {
            s  += __shfl_xor(s, m, 64);
            s2 += __shfl_xor(s2, m, 64);
        }
        const int wid = t >> 6, lane = t & 63;
        if (lane == 0) { ssum[wid] = s; ssum2[wid] = s2; }
        __syncthreads();
        s  = ssum[0] + ssum[1] + ssum[2] + ssum[3];
        s2 = ssum2[0] + ssum2[1] + ssum2[2] + ssum2[3];
        const float mu  = s * (1.f / 1024.f);
        const float var = s2 * (1.f / 1024.f) - mu * mu;
        const float rs  = rsqrtf(var + 1e-5f);
        float4 g = ((const float4*)gamma)[t];
        float4 b = ((const float4*)beta)[t];
        bf16x4 o;
        o[0] = (bf16)((v.x - mu) * rs * g.x + b.x);
        o[1] = (bf16)((v.y - mu) * rs * g.y + b.y);
        o[2] = (bf16)((v.z - mu) * rs * g.z + b.z);
        o[3] = (bf16)((v.w - mu) * rs * g.w + b.w);
        ((bf16x4*)(h + (size_t)blk * 1024))[t] = o;
    } else {
        // ---- transpose + cast fp32 -> bf16 (W[k][n] -> WT[n][k]) ----
        const int z = blk - 4096;
        const float* W; bf16* D;
        switch (z >> 10) {
            case 0: W = W0; D = D0; break;
            case 1: W = W1; D = D1; break;
            case 2: W = W2; D = D2; break;
            default: W = W3; D = D3; break;
        }
        const int bi = (z & 1023) >> 5, bj = z & 31;
        const int tx = t & 31, ty = t >> 5;  // 32 x 8
#pragma unroll
        for (int i = 0; i < 4; i++) {
            tile[ty + i * 8][tx] = W[(size_t)(bi * 32 + ty + i * 8) * 1024 + bj * 32 + tx];
        }
        __syncthreads();
#pragma unroll
        for (int i = 0; i < 4; i++) {
            D[(size_t)(bj * 32 + ty + i * 8) * 1024 + bi * 32 + tx] =
                (bf16)tile[tx][ty + i * 8];
        }
    }
}

// ---------------- GEMM: C[M][N] = A[M][K] @ BT[N][K]^T ----------------------
// 128x128 tile, BK=32, 4 waves (each 64x64), mfma 16x16x32 bf16.
// XCD-swizzled grid (nwg % 8 == 0 -> bijective).
// EPI 0: epilogue through per-wave LDS quadrant -> coalesced bf16x8 stores.
// EPI 1: epilogue through per-wave LDS quadrant -> coalesced float4
//        resid-load + store (+bo).
template <int EPI>
__global__ void gemm_kernel(const bf16* __restrict__ A, const bf16* __restrict__ BT,
                            int N, int K,
                            bf16* __restrict__ Cb,
                            const float* __restrict__ b0, const float* __restrict__ b1,
                            const float* __restrict__ b2, bf16* __restrict__ Vt,
                            float* __restrict__ Cf, const float* __restrict__ bo,
                            const float* __restrict__ resid) {
    __shared__ bf16 Asm[128][32];
    __shared__ bf16 Bsm[128][32];
    const int tid = threadIdx.x;
    const int lane = tid & 63, wave = tid >> 6;
    const int wr = wave >> 1, wc = wave & 1;
    // XCD-aware bijective block swizzle
    const int nwg = gridDim.x * gridDim.y;
    const int bid0 = blockIdx.y * gridDim.x + blockIdx.x;
    const int bid = (bid0 & 7) * (nwg >> 3) + (bid0 >> 3);
    const int tileN = (bid % gridDim.x) * 128;
    const int tileM = (bid / gridDim.x) * 128;
    const int row16 = lane & 15, g = lane >> 4;

    f32x4 acc[4][4] = {};

    for (int kt = 0; kt < K; kt += 32) {
#pragma unroll
        for (int i = 0; i < 2; i++) {  // A tile: 512 chunks of 16B
            int c = tid + i * 256;
            int r = c >> 2, cb = (c & 3) * 16;
            const char* g_ = (const char*)(A + (size_t)(tileM + r) * K + kt) + cb;
            char* l_ = (char*)&Asm[0][0] + c * 16;
            __builtin_amdgcn_global_load_lds(AS1U(g_), AS3U(l_), 16, 0, 0);
        }
#pragma unroll
        for (int i = 0; i < 2; i++) {  // B tile
            int c = tid + i * 256;
            int r = c >> 2, cb = (c & 3) * 16;
            const char* g_ = (const char*)(BT + (size_t)(tileN + r) * K + kt) + cb;
            char* l_ = (char*)&Bsm[0][0] + c * 16;
            __builtin_amdgcn_global_load_lds(AS1U(g_), AS3U(l_), 16, 0, 0);
        }
        __syncthreads();
        bf16x8 af[4], bfr[4];
#pragma unroll
        for (int m = 0; m < 4; m++)
            af[m] = *(const bf16x8*)&Asm[wr * 64 + m * 16 + row16][g * 8];
#pragma unroll
        for (int n = 0; n < 4; n++)
            bfr[n] = *(const bf16x8*)&Bsm[wc * 64 + n * 16 + row16][g * 8];
#pragma unroll
        for (int m = 0; m < 4; m++)
#pragma unroll
            for (int n = 0; n < 4; n++)
                acc[m][n] = __builtin_amdgcn_mfma_f32_16x16x32_bf16(af[m], bfr[n],
                                                                   acc[m][n], 0, 0, 0);
        __syncthreads();
    }

    if constexpr (EPI == 0) {
        // ---- epilogue via per-wave 8KB LDS quadrant (no cross-wave sync) ----
        __shared__ bf16 Ep[4][64][64];
        char* ep = (char*)&Ep[wave][0][0];
        const bool isV = (tileN >= 2048);
        if (!isV) {
#pragma unroll
            for (int n = 0; n < 4; n++) {
                const int cl = n * 16 + row16;
                const int gc = tileN + wc * 64 + cl;
                const float bias = gc < 1024 ? b0[gc] : b1[gc - 1024];
                const float scl = gc < 1024 ? 0.18033688011112042f : 1.f;
#pragma unroll
                for (int m = 0; m < 4; m++)
#pragma unroll
                    for (int j = 0; j < 4; j++) {
                        const int rl = m * 16 + g * 4 + j;
                        const float v = (acc[m][n][j] + bias) * scl;
                        *(bf16*)(ep + rl * 128 + ((cl * 2) ^ ((rl & 7) << 4))) = (bf16)v;
                    }
            }
        } else {
#pragma unroll
            for (int n = 0; n < 4; n++) {
                const int dl = n * 16 + row16;
                const float bias = b2[(tileN - 2048) + wc * 64 + dl];
#pragma unroll
                for (int m = 0; m < 4; m++)
#pragma unroll
                    for (int j = 0; j < 4; j++) {
                        const int tl = m * 16 + g * 4 + j;
                        const float v = fmaxf(acc[m][n][j] + bias, 0.f);
                        *(bf16*)(ep + dl * 128 + ((tl * 2) ^ ((dl & 7) << 4))) = (bf16)v;
                    }
            }
        }
        asm volatile("s_waitcnt lgkmcnt(0)" ::: "memory");
        __builtin_amdgcn_sched_barrier(0);
        if (!isV) {
#pragma unroll
            for (int it = 0; it < 8; it++) {
                const int rl = (lane >> 3) + it * 8;
                const bf16x8 vrow = *(const bf16x8*)(ep + rl * 128 +
                                                     (((lane & 7) * 16) ^ ((rl & 7) << 4)));
                const int gr = tileM + wr * 64 + rl;
                const int gc = tileN + wc * 64 + (lane & 7) * 8;
                *(bf16x8*)&Cb[(size_t)gr * N + gc] = vrow;
            }
        } else {
            const int bb = tileM >> 11;
            const int tbase = (tileM & 2047) + wr * 64 + (lane & 7) * 8;
#pragma unroll
            for (int it = 0; it < 8; it++) {
                const int dl = (lane >> 3) + it * 8;
                const bf16x8 vrow = *(const bf16x8*)(ep + dl * 128 +
                                                     (((lane & 7) * 16) ^ ((dl & 7) << 4)));
                const int gd = (tileN - 2048) + wc * 64 + dl;
                const int hh = gd >> 6, dd = gd & 63;
                *(bf16x8*)&Vt[(((size_t)bb * 16 + hh) * 64 + dd) * 2048 + tbase] = vrow;
            }
        }
    } else {
        // EPI 1: epilogue via per-wave 16.5KB fp32 LDS quadrant;
        // coalesced float4 resid-load + add + store.
        __shared__ float Epf[4][64][66];
        float* ep = &Epf[wave][0][0];
#pragma unroll
        for (int n = 0; n < 4; n++) {
            const int cl = n * 16 + row16;
            const float bias = bo[tileN + wc * 64 + cl];
#pragma unroll
            for (int m = 0; m < 4; m++)
#pragma unroll
                for (int j = 0; j < 4; j++) {
                    const int rl = m * 16 + g * 4 + j;
                    ep[rl * 66 + cl] = acc[m][n][j] + bias;
                }
        }
        asm volatile("s_waitcnt lgkmcnt(0)" ::: "memory");
        __builtin_amdgcn_sched_barrier(0);
        const int rl0 = lane >> 4;         // 0..3
        const int cl0 = (lane & 15) * 4;   // 0..60
#pragma unroll
        for (int it = 0; it < 16; it++) {
            const int rl = rl0 + it * 4;
            float4 v = *(const float4*)&ep[rl * 66 + cl0];
            const int gr = tileM + wr * 64 + rl;
            const int gc = tileN + wc * 64 + cl0;
            const float4 rv = *(const float4*)&resid[(size_t)gr * N + gc];
            v.x += rv.x; v.y += rv.y; v.z += rv.z; v.w += rv.w;
            *(float4*)&Cf[(size_t)gr * N + gc] = v;
        }
    }
}

// ---------------- flash attention, 32x32 MFMA, in-block KV split ------------
// grid 512 blocks (XCD-grouped), 512 threads = 8 waves.
// Waves 0-3: q-subtiles x KV[0,1024); waves 4-7: same q x KV[1024,2048).
// Fixed-max softmax (Q pre-scaled by 0.125*log2(e)).
// Softmax denominator l computed by MFMA against a ones-fragment: lands in
// accO's row layout (no tree sums, no cross-lane shuffles).
// Partials combine by addition in LDS at the end: O = (U0+U1)/(L0+L1).
__global__ __launch_bounds__(512, 4)
void attn_kernel(const bf16* __restrict__ qkv, const bf16* __restrict__ Vt,
                 bf16* __restrict__ Obuf) {
    const int bid = blockIdx.x;
    const int swz = (bid & 7) * 64 + (bid >> 3);  // 4 heads per XCD
    const int bh = swz >> 4, qt = swz & 15;
    const int b = bh >> 4, h = bh & 15;
    const int qbase = qt * 128;
    const int tid = threadIdx.x;
    const int lane = tid & 63, wv = tid >> 6;      // 8 waves
    const int half = wv >> 2, qw = wv & 3;
    const int c = lane & 31, p = lane >> 5;

    __shared__ bf16 Kl[2][2][64][64];  // [half][slot] 32 KB
    __shared__ bf16 Vl[2][2][64][64];  // [half][slot] 32 KB

    // Q B-frags (col q = c, k: d = ch*16 + p*8 + j), loop-invariant
    const bf16* qrow = qkv + (size_t)(b * 2048 + qbase + qw * 32 + c) * 3072 + h * 64;
    bf16x8 qf[4];
#pragma unroll
    for (int ch = 0; ch < 4; ch++)
        qf[ch] = *(const bf16x8*)(qrow + ch * 16 + p * 8);

    // staging: each half's 256 threads stage their half's K,V tile (4x16B each)
    const char* kgbase = (const char*)(qkv + (size_t)b * 2048 * 3072 + 1024 + h * 64)
                         + (size_t)(half * 1024) * 6144;
    const char* vgbase = (const char*)(Vt + (size_t)bh * 64 * 2048) + half * 2048;
    const int ht = tid & 255;
    const char* kgp[2]; const char* vgp[2]; int ldo[2];
#pragma unroll
    for (int i = 0; i < 2; i++) {
        const int cc = ht + i * 256;
        const int srow = cc >> 3;
        const int scol = ((cc & 7) * 16) ^ ((srow & 7) << 4);
        kgp[i] = kgbase + (size_t)srow * 6144 + scol;  // srow = token
        vgp[i] = vgbase + (size_t)srow * 4096 + scol;  // srow = d; scol = tok bytes
        ldo[i] = cc * 16;
    }
    char* kldb = (char*)&Kl[half][0][0][0];
    char* vldb = (char*)&Vl[half][0][0][0];

    auto stage = [&](int t, int slot) {
        const size_t ko = (size_t)t * (64 * 6144);  // 64 tokens fwd in qkv
        const size_t vo = (size_t)t * 128;          // 64 tokens * 2B fwd in Vt
        const int sb = slot * 8192;
#pragma unroll
        for (int i = 0; i < 2; i++) {
            __builtin_amdgcn_global_load_lds(AS1U(kgp[i] + ko), AS3U(kldb + sb + ldo[i]), 16, 0, 0);
            __builtin_amdgcn_global_load_lds(AS1U(vgp[i] + vo), AS3U(vldb + sb + ldo[i]), 16, 0, 0);
        }
    };

    f32x16 accO[2] = {};
    f32x16 accL = {};                 // l via ones-MFMA, row layout == accO
    const f32x16 z16 = {};            // persistent zero C-operand
    const u32 one2 = 0x3F803F80u;     // bf16 1.0 pair
    const u32x4 onesw = {one2, one2, one2, one2};
    const bf16x8 onesf = __builtin_bit_cast(bf16x8, onesw);

    auto compute = [&](int slot) {
        const char* Kb = (const char*)&Kl[half][slot][0][0];
        const char* Vb = (const char*)&Vl[half][slot][0][0];
#pragma unroll
        for (int cc = 0; cc < 2; cc++) {
            // S^T = K @ Q^T : col q = c, row tok = cc*32 + (r&3)+8*(r>>2)+4*p
            const int tok = cc * 32 + c;  // A-frag row
            const bf16x8 kf0 = *(const bf16x8*)(Kb + tok * 128 + ((0 * 32 + p * 16) ^ ((tok & 7) << 4)));
            f32x16 accT = __builtin_amdgcn_mfma_f32_32x32x16_bf16(kf0, qf[0], z16, 0, 0, 0);
#pragma unroll
            for (int ch = 1; ch < 4; ch++) {
                const bf16x8 kf = *(const bf16x8*)(Kb + tok * 128 +
                                                   ((ch * 32 + p * 16) ^ ((tok & 7) << 4)));
                accT = __builtin_amdgcn_mfma_f32_32x32x16_bf16(kf, qf[ch], accT, 0, 0, 0);
            }
            // fixed-max softmax: P = exp2(S) (Q pre-scaled)
            float pv[16];
#pragma unroll
            for (int r = 0; r < 16; r++) pv[r] = exp2f(accT[r]);
            // pack to bf16 pairs (tok order (0,1),(2,3),... per lane)
            u32 k01 = pack2(pv[0], pv[1]),  k23 = pack2(pv[2], pv[3]);
            u32 k45 = pack2(pv[4], pv[5]),  k67 = pack2(pv[6], pv[7]);
            u32 k89 = pack2(pv[8], pv[9]),  kab = pack2(pv[10], pv[11]);
            u32 kcd = pack2(pv[12], pv[13]), kef = pack2(pv[14], pv[15]);
            // v_permlane32_swap_b32 dst, src : dst.lo <-> src.hi
            asm("v_permlane32_swap_b32 %0, %1" : "+v"(k45), "+v"(k01));
            asm("v_permlane32_swap_b32 %0, %1" : "+v"(k67), "+v"(k23));
            asm("v_permlane32_swap_b32 %0, %1" : "+v"(kcd), "+v"(k89));
            asm("v_permlane32_swap_b32 %0, %1" : "+v"(kef), "+v"(kab));
            u32x4 w0w = {k01, k23, k45, k67};
            u32x4 w1w = {k89, kab, kcd, kef};
            const bf16x8 pf0 = __builtin_bit_cast(bf16x8, w0w);
            const bf16x8 pf1 = __builtin_bit_cast(bf16x8, w1w);
            // l[q] += sum_k P[q][k] : MFMA with B = ones (matrix pipe, ~idle)
            accL = __builtin_amdgcn_mfma_f32_32x32x16_bf16(pf0, onesf, accL, 0, 0, 0);
            accL = __builtin_amdgcn_mfma_f32_32x32x16_bf16(pf1, onesf, accL, 0, 0, 0);
            // PV: O[q][d] += P @ V ; B-frag: col d = dc*32+c, k tok = cc*32+w*16+p*8+j
#pragma unroll
            for (int dc = 0; dc < 2; dc++) {
                const int rd = dc * 32 + c;
                const int sw = (rd & 7) << 4;
                const bf16x8 vf0 = *(const bf16x8*)(Vb + rd * 128 + ((cc * 64 + p * 16) ^ sw));
                const bf16x8 vf1 = *(const bf16x8*)(Vb + rd * 128 + ((cc * 64 + 32 + p * 16) ^ sw));
                accO[dc] = __builtin_amdgcn_mfma_f32_32x32x16_bf16(pf0, vf0, accO[dc], 0, 0, 0);
                accO[dc] = __builtin_amdgcn_mfma_f32_32x32x16_bf16(pf1, vf1, accO[dc], 0, 0, 0);
            }
        }
    };

#define KV_SYNC() do { \
        asm volatile("s_waitcnt vmcnt(0)" ::: "memory"); \
        __builtin_amdgcn_s_barrier(); \
        asm volatile("" ::: "memory"); \
    } while (0)

    stage(0, 0);
#pragma unroll 1
    for (int t = 0; t < 14; t += 2) {
        KV_SYNC(); stage(t + 1, 1); compute(0);
        KV_SYNC(); stage(t + 2, 0); compute(1);
    }
    KV_SYNC(); stage(15, 1); compute(0);
    KV_SYNC(); compute(1);
#undef KV_SYNC

    // ---- combine the two KV halves via LDS (reuse ring memory) ----
    __syncthreads();
    float* ex = (float*)&Kl[0][0][0][0];   // 50.2 KB of 64 KB
    const int xb = (qw * 64 + lane) * 49;  // stride 49 -> conflict-free
    if (half) {
#pragma unroll
        for (int dc = 0; dc < 2; dc++)
#pragma unroll
            for (int r = 0; r < 16; r++) ex[xb + dc * 16 + r] = accO[dc][r];
#pragma unroll
        for (int r = 0; r < 16; r++) ex[xb + 32 + r] = accL[r];
    }
    __syncthreads();
    if (!half) {
#pragma unroll
        for (int dc = 0; dc < 2; dc++)
#pragma unroll
            for (int r = 0; r < 16; r++) accO[dc][r] += ex[xb + dc * 16 + r];
#pragma unroll
        for (int r = 0; r < 16; r++) accL[r] += ex[xb + 32 + r];
        // O /= l (l already in row layout, full k-range), store [b][h][t][d]
        bf16* ob = Obuf + ((size_t)bh * 2048 + qbase + qw * 32) * 64;
#pragma unroll
        for (int r = 0; r < 16; r++) {
            const float inv = 1.f / accL[r];
            const int row = (r & 3) + 8 * (r >> 2) + 4 * p;
            ob[(size_t)row * 64 + c]      = (bf16)(accO[0][r] * inv);
            ob[(size_t)row * 64 + 32 + c] = (bf16)(accO[1][r] * inv);
        }
    }
}

extern "C" void kernel_launch(void* const* d_in, const int* in_sizes, int n_in,
                              void* d_out, int out_size, void* d_ws, size_t ws_size,
                              hipStream_t stream) {
    const float* q     = (const float*)d_in[0];
    const float* gamma = (const float*)d_in[3];
    const float* beta  = (const float*)d_in[4];
    const float* Wq    = (const float*)d_in[5];
    const float* bq    = (const float*)d_in[6];
    const float* Wk    = (const float*)d_in[7];
    const float* bk    = (const float*)d_in[8];
    const float* Wv    = (const float*)d_in[9];
    const float* bv    = (const float*)d_in[10];
    const float* Wo    = (const float*)d_in[11];
    const float* bo    = (const float*)d_in[12];
    float* out = (float*)d_out;

    char* ws = (char*)d_ws;
    bf16* h     = (bf16*)(ws);                          // 8 MB
    bf16* WcatT = (bf16*)(ws + (8u << 20));             // 6 MB  [3072][1024]
    bf16* WoT   = (bf16*)(ws + (14u << 20));            // 2 MB  [1024][1024]
    bf16* qkv   = (bf16*)(ws + (16u << 20));            // 24 MB [4096][3072] (Q,K used)
    bf16* Obuf  = (bf16*)(ws + (40u << 20));            // 8 MB  [B][H][T][64]
    bf16* Vtb   = (bf16*)(ws + (48u << 20));            // 8 MB  [B][H][64][T]

    prep_kernel<<<8192, 256, 0, stream>>>(q, gamma, beta, h,
                                          Wq, Wk, Wv, Wo,
                                          WcatT, WcatT + (size_t)1024 * 1024,
                                          WcatT + (size_t)2048 * 1024, WoT);

    gemm_kernel<0><<<dim3(24, 32), 256, 0, stream>>>(h, WcatT, 3072, 1024,
                                                     qkv, bq, bk, bv, Vtb,
                                                     nullptr, nullptr, nullptr);

    attn_kernel<<<512, 512, 0, stream>>>(qkv, Vtb, Obuf);

    gemm_kernel<1><<<dim3(8, 32), 256, 0, stream>>>(Obuf, WoT, 1024, 1024,
                                                    nullptr, nullptr, nullptr, nullptr, nullptr,
                                                    out, bo, q);
}